// Round 4
// baseline (3810.353 us; speedup 1.0000x reference)
//
#include <hip/hip_runtime.h>
#include <math.h>

// Sparse voxel conv network, H=3 channels, 6 conv layers + 20-class head.
// Dense voxel grid per layer: voxelize -> memset -> scatter-add ->
// 27-tap gather-conv (relu fused; last layer fuses 3->20 head).
//
// Voxelize semantics: XLA folds  pts / vs  ->  pts * (1/vs)  with the
// reciprocal rounded in f32:  1/0.02f -> 50.0f, 1/0.04f -> 25.0f,
// 1/0.08f -> 12.5f (each 0.29 ulp from true recip, rounds to the nice value).
// So we must use floorf(x * inv_vs), NOT floorf(x / vs)  (true f32 division
// differs on ~dozens of boundary points -> the 2.82 absmax seen in r1/r3).
//
// Workspace: d_ws holds grid (100.4 MB) + flat ids (8 MB).  Feature
// ping-pong buffers live inside d_out (160 MB >> 48 MB needed); every call
// fully rewrites them before use -> deterministic, no races.

static constexpr int THREADS = 256;

// ---------------- voxelize: flat voxel id per point ------------------------
__global__ void __launch_bounds__(THREADS)
voxelize_kernel(const float* __restrict__ coords,  // [3, n]
                int* __restrict__ flat,            // [n]
                float inv_vs, int G, int n)
{
    int i = blockIdx.x * blockDim.x + threadIdx.x;
    if (i >= n) return;
    float x = coords[i];
    float y = coords[n + i];
    float z = coords[2 * n + i];
    int vx = (int)floorf(x * inv_vs) + 1;   // matches XLA's recip-mul fold
    int vy = (int)floorf(y * inv_vs) + 1;
    int vz = (int)floorf(z * inv_vs) + 1;
    flat[i] = (vx * G + vy) * G + vz;
}

// ---------------- scatter: pool point features into voxel grid -------------
__global__ void __launch_bounds__(THREADS)
scatter_kernel(const int* __restrict__ flat,
               const float* __restrict__ feat,    // [n, 3]
               float* __restrict__ grid,          // [G^3, 3]
               int n)
{
    int i = blockIdx.x * blockDim.x + threadIdx.x;
    if (i >= n) return;
    int f = flat[i];
    atomicAdd(&grid[3 * f + 0], feat[3 * i + 0]);
    atomicAdd(&grid[3 * f + 1], feat[3 * i + 1]);
    atomicAdd(&grid[3 * f + 2], feat[3 * i + 2]);
}

// ---------------- gather-conv: 27-tap stencil per point --------------------
// W layout: [3,3,3,Cin=3,Cout=3]. transpose => use W[1-dx][1-dy][1-dz].
template <bool FLIP, bool FUSE_GEN>
__global__ void __launch_bounds__(THREADS)
gather_conv_kernel(const int* __restrict__ flat,
                   const float* __restrict__ grid,    // [G^3, 3]
                   const float* __restrict__ W,       // [243]
                   const float* __restrict__ bias,    // [3] or null
                   const float* __restrict__ w_gen,   // [3,20] (FUSE_GEN)
                   const float* __restrict__ b_gen,   // [20]   (FUSE_GEN)
                   float* __restrict__ out,           // [n,3] or [n,20]
                   int G, int n)
{
    __shared__ float sW[243];
    __shared__ float sB[3];
    __shared__ float sG[60];
    __shared__ float sGB[20];
    int t = threadIdx.x;
    if (t < 243) sW[t] = W[t];
    if (t < 3)   sB[t] = bias ? bias[t] : 0.0f;
    if (FUSE_GEN) {
        if (t < 60) sG[t]  = w_gen[t];
        if (t < 20) sGB[t] = b_gen[t];
    }
    __syncthreads();

    int i = blockIdx.x * blockDim.x + t;
    if (i >= n) return;
    int f = flat[i];

    float acc0 = sB[0], acc1 = sB[1], acc2 = sB[2];

    #pragma unroll
    for (int dx = -1; dx <= 1; ++dx) {
        #pragma unroll
        for (int dy = -1; dy <= 1; ++dy) {
            // voxels (dz=-1,0,1) are contiguous: 9 floats in one row
            int base = f + (dx * G + dy) * G - 1;
            const float* g = &grid[3 * base];
            float gv[9];
            #pragma unroll
            for (int q = 0; q < 9; ++q) gv[q] = g[q];
            #pragma unroll
            for (int dz = -1; dz <= 1; ++dz) {
                const int a = FLIP ? (1 - dx) : (1 + dx);
                const int b = FLIP ? (1 - dy) : (1 + dy);
                const int c = FLIP ? (1 - dz) : (1 + dz);
                const float* w = &sW[((a * 3 + b) * 3 + c) * 9];  // [ci,co]
                float g0 = gv[(dz + 1) * 3 + 0];
                float g1 = gv[(dz + 1) * 3 + 1];
                float g2 = gv[(dz + 1) * 3 + 2];
                acc0 += g0 * w[0] + g1 * w[3] + g2 * w[6];
                acc1 += g0 * w[1] + g1 * w[4] + g2 * w[7];
                acc2 += g0 * w[2] + g1 * w[5] + g2 * w[8];
            }
        }
    }
    acc0 = fmaxf(acc0, 0.0f);
    acc1 = fmaxf(acc1, 0.0f);
    acc2 = fmaxf(acc2, 0.0f);

    if (FUSE_GEN) {
        float* o = out + (size_t)i * 20;
        #pragma unroll
        for (int c = 0; c < 20; ++c)
            o[c] = acc0 * sG[c] + acc1 * sG[20 + c] + acc2 * sG[40 + c] + sGB[c];
    } else {
        out[3 * i + 0] = acc0;
        out[3 * i + 1] = acc1;
        out[3 * i + 2] = acc2;
    }
}

// ---------------------------------------------------------------------------
extern "C" void kernel_launch(void* const* d_in, const int* in_sizes, int n_in,
                              void* d_out, int out_size, void* d_ws, size_t ws_size,
                              hipStream_t stream)
{
    const float* coords     = (const float*)d_in[0];   // [3,N]
    const float* pixel_vals = (const float*)d_in[1];   // [N,3]
    const float* w_enc1 = (const float*)d_in[2];
    const float* w_enc2 = (const float*)d_in[3];
    const float* w_enc3 = (const float*)d_in[4];
    const float* w_dec1 = (const float*)d_in[5];
    const float* b_dec1 = (const float*)d_in[6];
    const float* w_dec2 = (const float*)d_in[7];
    const float* b_dec2 = (const float*)d_in[8];
    const float* w_dec3 = (const float*)d_in[9];
    const float* b_dec3 = (const float*)d_in[10];
    const float* w_gen  = (const float*)d_in[11];
    const float* b_gen  = (const float*)d_in[12];

    const int n = in_sizes[0] / 3;

    // d_ws: grid (25,096,284 floats) | flat (n ints)  => ~108.4 MB total
    float* ws   = (float*)d_ws;
    float* grid = ws;
    int*   flat = (int*)(ws + 25096284);

    // d_out doubles as feature scratch: featA = words [0,3n), featB = [3n,6n).
    // Final fused kernel overwrites all of d_out with the real [n,20] output.
    float* out   = (float*)d_out;
    float* featA = out;
    float* featB = out + (size_t)n * 3;

    const int blocks = (n + THREADS - 1) / THREADS;

    const int   G1 = 203, G2 = 103, G3 = 53;
    // f32-rounded reciprocals of f32(0.02/0.04/0.08) — all land on exact values
    const float I1 = 50.0f, I2 = 25.0f, I3 = 12.5f;

    auto gridBytes = [](int G) { return (size_t)G * G * G * 3 * sizeof(float); };

    // ---- enc1: vs=0.02 ----
    voxelize_kernel<<<blocks, THREADS, 0, stream>>>(coords, flat, I1, G1, n);
    hipMemsetAsync(grid, 0, gridBytes(G1), stream);
    scatter_kernel<<<blocks, THREADS, 0, stream>>>(flat, pixel_vals, grid, n);
    gather_conv_kernel<false, false><<<blocks, THREADS, 0, stream>>>(
        flat, grid, w_enc1, nullptr, nullptr, nullptr, featA, G1, n);

    // ---- enc2: vs=0.04 ----
    voxelize_kernel<<<blocks, THREADS, 0, stream>>>(coords, flat, I2, G2, n);
    hipMemsetAsync(grid, 0, gridBytes(G2), stream);
    scatter_kernel<<<blocks, THREADS, 0, stream>>>(flat, featA, grid, n);
    gather_conv_kernel<false, false><<<blocks, THREADS, 0, stream>>>(
        flat, grid, w_enc2, nullptr, nullptr, nullptr, featB, G2, n);

    // ---- enc3: vs=0.08 ----
    voxelize_kernel<<<blocks, THREADS, 0, stream>>>(coords, flat, I3, G3, n);
    hipMemsetAsync(grid, 0, gridBytes(G3), stream);
    scatter_kernel<<<blocks, THREADS, 0, stream>>>(flat, featB, grid, n);
    gather_conv_kernel<false, false><<<blocks, THREADS, 0, stream>>>(
        flat, grid, w_enc3, nullptr, nullptr, nullptr, featA, G3, n);

    // ---- dec1: vs=0.08, transpose (flat ids unchanged from enc3) ----
    hipMemsetAsync(grid, 0, gridBytes(G3), stream);
    scatter_kernel<<<blocks, THREADS, 0, stream>>>(flat, featA, grid, n);
    gather_conv_kernel<true, false><<<blocks, THREADS, 0, stream>>>(
        flat, grid, w_dec1, b_dec1, nullptr, nullptr, featB, G3, n);

    // ---- dec2: vs=0.04, transpose ----
    voxelize_kernel<<<blocks, THREADS, 0, stream>>>(coords, flat, I2, G2, n);
    hipMemsetAsync(grid, 0, gridBytes(G2), stream);
    scatter_kernel<<<blocks, THREADS, 0, stream>>>(flat, featB, grid, n);
    gather_conv_kernel<true, false><<<blocks, THREADS, 0, stream>>>(
        flat, grid, w_dec2, b_dec2, nullptr, nullptr, featA, G2, n);

    // ---- dec3: vs=0.02, transpose, fused 3->20 head ----
    voxelize_kernel<<<blocks, THREADS, 0, stream>>>(coords, flat, I1, G1, n);
    hipMemsetAsync(grid, 0, gridBytes(G1), stream);
    scatter_kernel<<<blocks, THREADS, 0, stream>>>(flat, featA, grid, n);
    gather_conv_kernel<true, true><<<blocks, THREADS, 0, stream>>>(
        flat, grid, w_dec3, b_dec3, w_gen, b_gen, out, G1, n);
}

// Round 5
// 906.885 us; speedup vs baseline: 4.2016x; 4.2016x over previous
//
#include <hip/hip_runtime.h>
#include <math.h>

// Sparse voxel conv net (H=3, 6 convs + 20-class head), N=2M points.
//
// FAST PATH (voxel-space collapse): per-point conv output depends only on the
// point's voxel id, and voxel ids nest across scales (vx_c = ((vx_f-1)>>1)+1,
// exact in f32 because 1/vs folds to 50/25/12.5 and halving is exact). So:
//   scatter points once -> fine 4ch grid (count, sum pixel_vals)
//   enc convs: dense stencil, out = count * relu(conv) ; downsample = sum 8 kids
//   dec convs: dense stencil (flipped W, bias);  upsample(v) = c(v)*parent val
//   final: per-point lookup of fine voxel + 3->20 head.
// All heavy kernels are dense/coalesced; the only random-access kernels are the
// single point-scatter and the final single-voxel lookup.
//
// FALLBACK (proven round-4 path, 108 MB ws) if ws_size < fast-path need.

static constexpr int THREADS = 256;

// ========================== FAST PATH kernels ==============================

__global__ void __launch_bounds__(THREADS)
scatter4_kernel(const float* __restrict__ coords, const float* __restrict__ pv,
                int* __restrict__ flat, float* __restrict__ g4, int n)
{
    int i = blockIdx.x * blockDim.x + threadIdx.x;
    if (i >= n) return;
    float x = coords[i], y = coords[n + i], z = coords[2 * n + i];
    int vx = (int)floorf(x * 50.0f) + 1;   // XLA recip-mul semantics (r4-proven)
    int vy = (int)floorf(y * 50.0f) + 1;
    int vz = (int)floorf(z * 50.0f) + 1;
    int f = (vx * 203 + vy) * 203 + vz;
    flat[i] = f;
    float* c = g4 + 4 * (size_t)f;
    atomicAdd(c + 0, 1.0f);
    atomicAdd(c + 1, pv[3 * i + 0]);
    atomicAdd(c + 2, pv[3 * i + 1]);
    atomicAdd(c + 3, pv[3 * i + 2]);
}

// dense 27-tap conv over interior [1,G-2]^3 of a 4ch grid (ch0=count, ch1..3=f)
// out(u) = (cnt, m * relu(conv(in)(u) + bias)) with m = MULC ? cnt : 1.
template <int G, int E, bool FLIP, bool MULC, bool BIAS>
__global__ void __launch_bounds__(THREADS)
conv_dense_kernel(const float4* __restrict__ in, const float* __restrict__ W,
                  const float* __restrict__ bias, float4* __restrict__ out)
{
    __shared__ float sW[243];
    __shared__ float sB[3];
    int t = threadIdx.x;
    if (t < 243) sW[t] = W[t];
    if (t < 3)   sB[t] = BIAS ? bias[t] : 0.0f;
    __syncthreads();

    int i = blockIdx.x * blockDim.x + t;
    if (i >= E * E * E) return;
    unsigned ui = (unsigned)i;
    int z = (int)(ui % (unsigned)E) + 1;  unsigned q = ui / (unsigned)E;
    int y = (int)(q % (unsigned)E) + 1;
    int x = (int)(q / (unsigned)E) + 1;
    int base = (x * G + y) * G + z;

    float a0 = sB[0], a1 = sB[1], a2 = sB[2];
    float cnt = 0.0f;
    #pragma unroll
    for (int dx = -1; dx <= 1; ++dx) {
        #pragma unroll
        for (int dy = -1; dy <= 1; ++dy) {
            int r = base + (dx * G + dy) * G;
            float4 va = in[r - 1], vb = in[r], vc = in[r + 1];
            if (dx == 0 && dy == 0) cnt = vb.x;
            #pragma unroll
            for (int dz = -1; dz <= 1; ++dz) {
                const int ax = FLIP ? 1 - dx : 1 + dx;
                const int ay = FLIP ? 1 - dy : 1 + dy;
                const int az = FLIP ? 1 - dz : 1 + dz;
                const float* w = &sW[((ax * 3 + ay) * 3 + az) * 9];
                float g0, g1, g2;
                if (dz == -1)      { g0 = va.y; g1 = va.z; g2 = va.w; }
                else if (dz == 0)  { g0 = vb.y; g1 = vb.z; g2 = vb.w; }
                else               { g0 = vc.y; g1 = vc.z; g2 = vc.w; }
                a0 += g0 * w[0] + g1 * w[3] + g2 * w[6];
                a1 += g0 * w[1] + g1 * w[4] + g2 * w[7];
                a2 += g0 * w[2] + g1 * w[5] + g2 * w[8];
            }
        }
    }
    a0 = fmaxf(a0, 0.0f); a1 = fmaxf(a1, 0.0f); a2 = fmaxf(a2, 0.0f);
    if (MULC) { a0 *= cnt; a1 *= cnt; a2 *= cnt; }
    out[base] = make_float4(cnt, a0, a1, a2);
}

// coarse(v) = sum of 8 children, v in [1,Mc]^3; children of v are {2v-1, 2v}.
template <int Gc, int Gf, int Mc>
__global__ void __launch_bounds__(THREADS)
down4_kernel(const float4* __restrict__ fine, float4* __restrict__ coarse)
{
    int i = blockIdx.x * blockDim.x + threadIdx.x;
    if (i >= Mc * Mc * Mc) return;
    unsigned ui = (unsigned)i;
    int zc = (int)(ui % (unsigned)Mc) + 1;  unsigned q = ui / (unsigned)Mc;
    int yc = (int)(q % (unsigned)Mc) + 1;
    int xc = (int)(q / (unsigned)Mc) + 1;
    int xf = 2 * xc - 1, yf = 2 * yc - 1, zf = 2 * zc - 1;
    float4 s = make_float4(0, 0, 0, 0);
    #pragma unroll
    for (int a = 0; a < 2; ++a)
        #pragma unroll
        for (int b = 0; b < 2; ++b) {
            int r = ((xf + a) * Gf + (yf + b)) * Gf + zf;
            float4 u = fine[r], v = fine[r + 1];
            s.x += u.x + v.x; s.y += u.y + v.y;
            s.z += u.z + v.z; s.w += u.w + v.w;
        }
    coarse[(xc * Gc + yc) * Gc + zc] = s;
}

// outf(u) = (c(u), c(u) * coarse(parent(u)).yzw) over the FULL fine grid.
// cntsrc may alias outf (per-cell in-place is safe).
template <int Gf, int Gc>
__global__ void __launch_bounds__(THREADS)
up4_kernel(const float4* __restrict__ cntsrc, const float4* __restrict__ coarse,
           float4* __restrict__ outf)
{
    int i = blockIdx.x * blockDim.x + threadIdx.x;
    if (i >= Gf * Gf * Gf) return;
    unsigned ui = (unsigned)i;
    int z = (int)(ui % (unsigned)Gf);  unsigned q = ui / (unsigned)Gf;
    int y = (int)(q % (unsigned)Gf);
    int x = (int)(q / (unsigned)Gf);
    float cnt = cntsrc[i].x;
    int px = x > 0 ? ((x - 1) >> 1) + 1 : 0;
    int py = y > 0 ? ((y - 1) >> 1) + 1 : 0;
    int pz = z > 0 ? ((z - 1) >> 1) + 1 : 0;
    float4 p = coarse[(px * Gc + py) * Gc + pz];
    outf[i] = make_float4(cnt, cnt * p.y, cnt * p.z, cnt * p.w);
}

__global__ void __launch_bounds__(THREADS)
final_head_kernel(const int* __restrict__ flat, const float4* __restrict__ yF,
                  const float* __restrict__ wg, const float* __restrict__ bg,
                  float* __restrict__ out, int n)
{
    __shared__ float sG[60], sGB[20];
    int t = threadIdx.x;
    if (t < 60) sG[t] = wg[t];
    if (t < 20) sGB[t] = bg[t];
    __syncthreads();
    int i = blockIdx.x * blockDim.x + t;
    if (i >= n) return;
    float4 v = yF[flat[i]];
    float* o = out + (size_t)i * 20;
    #pragma unroll
    for (int c = 0; c < 20; ++c)
        o[c] = v.y * sG[c] + v.z * sG[20 + c] + v.w * sG[40 + c] + sGB[c];
}

// ===================== FALLBACK (round-4 proven) ===========================

__global__ void __launch_bounds__(THREADS)
voxelize_kernel(const float* __restrict__ coords, int* __restrict__ flat,
                float inv_vs, int G, int n)
{
    int i = blockIdx.x * blockDim.x + threadIdx.x;
    if (i >= n) return;
    int vx = (int)floorf(coords[i] * inv_vs) + 1;
    int vy = (int)floorf(coords[n + i] * inv_vs) + 1;
    int vz = (int)floorf(coords[2 * n + i] * inv_vs) + 1;
    flat[i] = (vx * G + vy) * G + vz;
}

__global__ void __launch_bounds__(THREADS)
scatter_kernel(const int* __restrict__ flat, const float* __restrict__ feat,
               float* __restrict__ grid, int n)
{
    int i = blockIdx.x * blockDim.x + threadIdx.x;
    if (i >= n) return;
    int f = flat[i];
    atomicAdd(&grid[3 * f + 0], feat[3 * i + 0]);
    atomicAdd(&grid[3 * f + 1], feat[3 * i + 1]);
    atomicAdd(&grid[3 * f + 2], feat[3 * i + 2]);
}

template <bool FLIP, bool FUSE_GEN>
__global__ void __launch_bounds__(THREADS)
gather_conv_kernel(const int* __restrict__ flat, const float* __restrict__ grid,
                   const float* __restrict__ W, const float* __restrict__ bias,
                   const float* __restrict__ w_gen, const float* __restrict__ b_gen,
                   float* __restrict__ out, int G, int n)
{
    __shared__ float sW[243];
    __shared__ float sB[3];
    __shared__ float sG[60];
    __shared__ float sGB[20];
    int t = threadIdx.x;
    if (t < 243) sW[t] = W[t];
    if (t < 3)   sB[t] = bias ? bias[t] : 0.0f;
    if (FUSE_GEN) {
        if (t < 60) sG[t]  = w_gen[t];
        if (t < 20) sGB[t] = b_gen[t];
    }
    __syncthreads();
    int i = blockIdx.x * blockDim.x + t;
    if (i >= n) return;
    int f = flat[i];
    float acc0 = sB[0], acc1 = sB[1], acc2 = sB[2];
    #pragma unroll
    for (int dx = -1; dx <= 1; ++dx) {
        #pragma unroll
        for (int dy = -1; dy <= 1; ++dy) {
            int base = f + (dx * G + dy) * G - 1;
            const float* g = &grid[3 * base];
            float gv[9];
            #pragma unroll
            for (int q = 0; q < 9; ++q) gv[q] = g[q];
            #pragma unroll
            for (int dz = -1; dz <= 1; ++dz) {
                const int a = FLIP ? (1 - dx) : (1 + dx);
                const int b = FLIP ? (1 - dy) : (1 + dy);
                const int c = FLIP ? (1 - dz) : (1 + dz);
                const float* w = &sW[((a * 3 + b) * 3 + c) * 9];
                float g0 = gv[(dz + 1) * 3 + 0];
                float g1 = gv[(dz + 1) * 3 + 1];
                float g2 = gv[(dz + 1) * 3 + 2];
                acc0 += g0 * w[0] + g1 * w[3] + g2 * w[6];
                acc1 += g0 * w[1] + g1 * w[4] + g2 * w[7];
                acc2 += g0 * w[2] + g1 * w[5] + g2 * w[8];
            }
        }
    }
    acc0 = fmaxf(acc0, 0.0f); acc1 = fmaxf(acc1, 0.0f); acc2 = fmaxf(acc2, 0.0f);
    if (FUSE_GEN) {
        float* o = out + (size_t)i * 20;
        #pragma unroll
        for (int c = 0; c < 20; ++c)
            o[c] = acc0 * sG[c] + acc1 * sG[20 + c] + acc2 * sG[40 + c] + sGB[c];
    } else {
        out[3 * i + 0] = acc0;
        out[3 * i + 1] = acc1;
        out[3 * i + 2] = acc2;
    }
}

// ---------------------------------------------------------------------------
extern "C" void kernel_launch(void* const* d_in, const int* in_sizes, int n_in,
                              void* d_out, int out_size, void* d_ws, size_t ws_size,
                              hipStream_t stream)
{
    const float* coords     = (const float*)d_in[0];
    const float* pixel_vals = (const float*)d_in[1];
    const float* w_enc1 = (const float*)d_in[2];
    const float* w_enc2 = (const float*)d_in[3];
    const float* w_enc3 = (const float*)d_in[4];
    const float* w_dec1 = (const float*)d_in[5];
    const float* b_dec1 = (const float*)d_in[6];
    const float* w_dec2 = (const float*)d_in[7];
    const float* b_dec2 = (const float*)d_in[8];
    const float* w_dec3 = (const float*)d_in[9];
    const float* b_dec3 = (const float*)d_in[10];
    const float* w_gen  = (const float*)d_in[11];
    const float* b_gen  = (const float*)d_in[12];

    const int n = in_sizes[0] / 3;
    const int blocks = (n + THREADS - 1) / THREADS;
    float* out = (float*)d_out;

    // ---- fast-path workspace layout (floats) ----
    constexpr size_t SZ_BIG1 = 33461712;            // 203^3*4 padded
    constexpr size_t SZ_G2   = 4370912;             // 103^3*4 padded
    constexpr size_t SZ_G3   = 595512;              // 53^3*4 padded
    const size_t nf = ((size_t)n + 3) & ~(size_t)3;
    size_t off_flat = SZ_BIG1;
    size_t off_g2   = off_flat + nf;
    size_t off_t2   = off_g2 + SZ_G2;
    size_t off_g3   = off_t2 + SZ_G2;
    size_t off_t3   = off_g3 + SZ_G3;
    size_t need     = (off_t3 + SZ_G3) * 4;
    const size_t fineBytes = (size_t)203 * 203 * 203 * 4 * sizeof(float);
    bool fast = (ws_size >= need) && ((size_t)out_size * 4 >= fineBytes);

    if (fast) {
        float* ws    = (float*)d_ws;
        float4* big1 = (float4*)ws;                       // scatter grid / yF
        int*    flat = (int*)(ws + off_flat);
        float4* g2   = (float4*)(ws + off_g2);
        float4* t2   = (float4*)(ws + off_t2);
        float4* g3   = (float4*)(ws + off_g3);
        float4* t3   = (float4*)(ws + off_t3);
        float4* T    = (float4*)d_out;                    // fine temp / gridD3

        auto nb = [](int cells) { return (cells + THREADS - 1) / THREADS; };
        constexpr int C1 = 201 * 201 * 201, C2 = 101 * 101 * 101, C3 = 51 * 51 * 51;
        constexpr int D2 = 100 * 100 * 100, D3 = 50 * 50 * 50;
        constexpr int F1 = 203 * 203 * 203, F2 = 103 * 103 * 103;

        hipMemsetAsync(big1, 0, SZ_BIG1 * 4, stream);
        hipMemsetAsync(g2,   0, SZ_G2 * 4, stream);
        hipMemsetAsync(g3,   0, SZ_G3 * 4, stream);
        hipMemsetAsync(t3,   0, SZ_G3 * 4, stream);

        // scatter points -> fine 4ch grid (+ flat ids)
        scatter4_kernel<<<blocks, THREADS, 0, stream>>>(
            coords, pixel_vals, flat, (float*)big1, n);

        // enc1: T = c1 * relu(conv(big1))      then down -> g2
        conv_dense_kernel<203, 201, false, true, false><<<nb(C1), THREADS, 0, stream>>>(
            big1, w_enc1, nullptr, T);
        down4_kernel<103, 203, 100><<<nb(D2), THREADS, 0, stream>>>(T, g2);

        // enc2: t2 = c2 * relu(conv(g2))       then down -> g3
        conv_dense_kernel<103, 101, false, true, false><<<nb(C2), THREADS, 0, stream>>>(
            g2, w_enc2, nullptr, t2);
        down4_kernel<53, 103, 50><<<nb(D3), THREADS, 0, stream>>>(t2, g3);

        // enc3: t3 = c3 * relu(conv(g3))   (this IS dec1's input grid)
        conv_dense_kernel<53, 51, false, true, false><<<nb(C3), THREADS, 0, stream>>>(
            g3, w_enc3, nullptr, t3);

        // dec1: g3 = relu(convT(t3) + b1)
        conv_dense_kernel<53, 51, true, false, true><<<nb(C3), THREADS, 0, stream>>>(
            t3, w_dec1, b_dec1, g3);

        // dec2 grid: g2(v) = (c2, c2 * g3[parent(v)])   (in-place on g2)
        up4_kernel<103, 53><<<nb(F2), THREADS, 0, stream>>>(g2, g3, g2);
        // dec2: t2 = relu(convT(g2) + b2)
        conv_dense_kernel<103, 101, true, false, true><<<nb(C2), THREADS, 0, stream>>>(
            g2, w_dec2, b_dec2, t2);

        // dec3 grid: T(u) = (c1, c1 * t2[parent(u)])   (counts from big1)
        up4_kernel<203, 103><<<nb(F1), THREADS, 0, stream>>>(big1, t2, T);
        // dec3: big1 = relu(convT(T) + b3)  (= yF)
        conv_dense_kernel<203, 201, true, false, true><<<nb(C1), THREADS, 0, stream>>>(
            T, w_dec3, b_dec3, big1);

        // final: out[p] = yF[flat[p]] @ w_gen + b_gen
        final_head_kernel<<<blocks, THREADS, 0, stream>>>(
            flat, big1, w_gen, b_gen, out, n);
        return;
    }

    // ---------------- fallback: proven round-4 path ------------------------
    float* ws   = (float*)d_ws;
    float* grid = ws;
    int*   flat = (int*)(ws + 25096284);
    float* featA = out;
    float* featB = out + (size_t)n * 3;

    const int   G1 = 203, G2 = 103, G3 = 53;
    const float I1 = 50.0f, I2 = 25.0f, I3 = 12.5f;
    auto gridBytes = [](int G) { return (size_t)G * G * G * 3 * sizeof(float); };

    voxelize_kernel<<<blocks, THREADS, 0, stream>>>(coords, flat, I1, G1, n);
    hipMemsetAsync(grid, 0, gridBytes(G1), stream);
    scatter_kernel<<<blocks, THREADS, 0, stream>>>(flat, pixel_vals, grid, n);
    gather_conv_kernel<false, false><<<blocks, THREADS, 0, stream>>>(
        flat, grid, w_enc1, nullptr, nullptr, nullptr, featA, G1, n);

    voxelize_kernel<<<blocks, THREADS, 0, stream>>>(coords, flat, I2, G2, n);
    hipMemsetAsync(grid, 0, gridBytes(G2), stream);
    scatter_kernel<<<blocks, THREADS, 0, stream>>>(flat, featA, grid, n);
    gather_conv_kernel<false, false><<<blocks, THREADS, 0, stream>>>(
        flat, grid, w_enc2, nullptr, nullptr, nullptr, featB, G2, n);

    voxelize_kernel<<<blocks, THREADS, 0, stream>>>(coords, flat, I3, G3, n);
    hipMemsetAsync(grid, 0, gridBytes(G3), stream);
    scatter_kernel<<<blocks, THREADS, 0, stream>>>(flat, featB, grid, n);
    gather_conv_kernel<false, false><<<blocks, THREADS, 0, stream>>>(
        flat, grid, w_enc3, nullptr, nullptr, nullptr, featA, G3, n);

    hipMemsetAsync(grid, 0, gridBytes(G3), stream);
    scatter_kernel<<<blocks, THREADS, 0, stream>>>(flat, featA, grid, n);
    gather_conv_kernel<true, false><<<blocks, THREADS, 0, stream>>>(
        flat, grid, w_dec1, b_dec1, nullptr, nullptr, featB, G3, n);

    voxelize_kernel<<<blocks, THREADS, 0, stream>>>(coords, flat, I2, G2, n);
    hipMemsetAsync(grid, 0, gridBytes(G2), stream);
    scatter_kernel<<<blocks, THREADS, 0, stream>>>(flat, featB, grid, n);
    gather_conv_kernel<true, false><<<blocks, THREADS, 0, stream>>>(
        flat, grid, w_dec2, b_dec2, nullptr, nullptr, featA, G2, n);

    voxelize_kernel<<<blocks, THREADS, 0, stream>>>(coords, flat, I1, G1, n);
    hipMemsetAsync(grid, 0, gridBytes(G1), stream);
    scatter_kernel<<<blocks, THREADS, 0, stream>>>(flat, featA, grid, n);
    gather_conv_kernel<true, true><<<blocks, THREADS, 0, stream>>>(
        flat, grid, w_dec3, b_dec3, w_gen, b_gen, out, G1, n);
}